// Round 2
// baseline (173.766 us; speedup 1.0000x reference)
//
#include <hip/hip_runtime.h>

constexpr int B_  = 4;
constexpr int T_  = 4096;
constexpr int C_  = 1024;
constexpr int H_  = 64;
constexpr int BT_ = B_ * T_;
constexpr int NUNIT_ = 1152;   // 512-key work units per batch: sum_qt (qt/32+1)

typedef __attribute__((ext_vector_type(4))) float f32x4;
typedef __attribute__((ext_vector_type(8))) short bf16x8;
typedef __attribute__((ext_vector_type(8))) unsigned short u16x8;
typedef __attribute__((ext_vector_type(4))) unsigned short u16x4;

__device__ __forceinline__ unsigned short f32_to_bf16(float f) {
    union { float f; unsigned int u; } v;
    v.f = f;
    unsigned int r = v.u + 0x7FFFu + ((v.u >> 16) & 1u);  // RNE
    return (unsigned short)(r >> 16);
}
__device__ __forceinline__ float bf16_to_f32(unsigned short us) {
    union { unsigned int u; float f; } v;
    v.u = (unsigned int)us << 16;
    return v.f;
}
// 2^x via v_exp_f32 (hardware transcendental); __exp2f does not exist in HIP.
__device__ __forceinline__ float exp2_hw(float x) {
    return __builtin_amdgcn_exp2f(x);
}

// ---- Kernel 0: W -> fragment-order Wt (unchanged) --------------------------
__global__ __launch_bounds__(256) void wconv_kernel(
    const float* __restrict__ Wq, const float* __restrict__ Wk,
    const float* __restrict__ Wv, unsigned short* __restrict__ Wt)
{
    const int tid  = threadIdx.x;
    const int wid  = blockIdx.x * 4 + (tid >> 6);   // 0..383 = 12 ntiles x 32 ksteps
    const int lane = tid & 63;
    const int q    = lane >> 4, c = lane & 15;
    const int ntile = wid >> 5;
    const int kstep = wid & 31;
    const int n = ntile * 16 + c;                   // 0..191
    const int m = n >> 6;
    const float* W = (m == 0) ? Wq : (m == 1) ? Wk : Wv;
    const int ncol = n & 63;
    const int k0 = kstep * 32 + q * 8;
    u16x8 pk;
#pragma unroll
    for (int j = 0; j < 8; j++) pk[j] = f32_to_bf16(W[(size_t)(k0 + j) * H_ + ncol]);
    *(u16x8*)(Wt + (size_t)wid * 512 + lane * 8) = pk;
}

// ---- Kernel 1: QKV projection, fused fragment-order epilogue ---------------
// Round-14: single x read (was 2x in round-13): 256-thread / 4-wave blocks,
// each block owns 16 rows and ALL 192 output cols (wave w -> cols w*48..+47).
// x traffic 134 MB -> 67 MB; still double-buffered LDS, one barrier per
// 64-K step, prefetch issued after the barrier (empty vmem queue at barrier).
// 1024 blocks -> 4 blocks/CU -> 4 independent barrier groups/CU.
__global__ __launch_bounds__(256, 4) void proj_kernel(
    const float* __restrict__ x, const unsigned short* __restrict__ Wt,
    unsigned short* __restrict__ Qf, unsigned short* __restrict__ Kf,
    unsigned short* __restrict__ Vf)
{
    __shared__ __align__(16) unsigned short xs[2][16][72];
    const int t    = threadIdx.x;
    const int r0   = blockIdx.x * 16;
    const int w    = t >> 6;             // 0..3
    const int lane = t & 63;
    const int quad = lane >> 4;
    const int c    = lane & 15;
    const int nh   = w * 48;             // wave's 48-col n-chunk
    const int row  = t >> 4;             // 16 rows, 16 threads/row
    const int koff = (t & 15) * 4;       // one f32x4 per thread per 64-col tile

    f32x4 acc[3];
#pragma unroll
    for (int j = 0; j < 3; j++) acc[j] = {0.f, 0.f, 0.f, 0.f};

    const float* xp = x + (size_t)(r0 + row) * C_ + koff;
    f32x4 v0 = *(const f32x4*)xp;        // tile kk=0

    int p = 0;
    for (int kk = 0; kk < C_; kk += 64) {
        u16x4 pk0;
#pragma unroll
        for (int i = 0; i < 4; i++) pk0[i] = f32_to_bf16(v0[i]);
        *(u16x4*)&xs[p][row][koff] = pk0;
        __syncthreads();                  // no vmem outstanding: free drain
        if (kk + 64 < C_) v0 = *(const f32x4*)(xp + kk + 64);  // prefetch next
#pragma unroll
        for (int ks = 0; ks < 64; ks += 32) {
            const bf16x8 a0 = *(const bf16x8*)&xs[p][c][ks + quad * 8];
            const unsigned short* bp =
                Wt + ((size_t)(nh >> 4) * 32 + ((kk + ks) >> 5)) * 512 + lane * 8;
#pragma unroll
            for (int j = 0; j < 3; j++) {
                const bf16x8 bj = *(const bf16x8*)(bp + (size_t)j * 32 * 512);
                acc[j] = __builtin_amdgcn_mfma_f32_16x16x32_bf16(a0, bj, acc[j], 0, 0, 0);
            }
        }
        p ^= 1;
    }

    // fused fragment-order epilogue (S = r0; 16-aligned)
    const int S   = r0;
    const int bS  = S >> 12;
    const int cc0 = quad * 4;
#pragma unroll
    for (int j = 0; j < 3; j++) {
        const int nt = nh + j * 16;   // wave-uniform matrix select
        if (nt < 128) {               // Q (nt<64) or K
            const int d0 = (nt < 64) ? nt : nt - 64;
            unsigned short* base = (nt < 64) ? Qf : Kf;
            const int t16  = (S & 4095) >> 4;
            const int half = d0 >> 5;
            const int q8   = ((d0 >> 4) & 1) * 2 + (c >> 3);
            const int j8   = c & 7;
            unsigned short* pq = base + ((size_t)(bS * 256 + t16)) * 1024
                               + half * 512 + q8 * 128 + j8;
#pragma unroll
            for (int r = 0; r < 4; r++) pq[(cc0 + r) * 8] = f32_to_bf16(acc[j][r]);
        } else {                      // V
            const int d0  = nt - 128;
            const int k32 = (S & 4095) >> 5;
            const int ht  = d0 >> 4;
            const int sq  = (S & 31) >> 3;   // 0 or 2
            unsigned short* pv = Vf + (((size_t)(bS * 128 + k32)) * 4 + ht) * 512 + c * 8;
#pragma unroll
            for (int r = 0; r < 4; r++) {
                const int cc = cc0 + r;
                pv[(sq + (cc >> 3)) * 128 + (cc & 7)] = f32_to_bf16(acc[j][r]);
            }
        }
    }
}

// ---- Kernel 2: causal flash attention ------------------------------------
// Round-14: latency-chain surgery.
//  - K chunk double-buffered IN PLACE: after the QK MFMAs consume kC, the
//    next chunk's K loads overwrite kC -> ~300cy L2 latency hides under
//    softmax+PV instead of heading every chunk.
//  - mask+scale folded into S in place (sc[16] array gone).
//  - max: depth-5 tree (was 15-deep serial chain); lsum: 4 independent
//    chains (was 16-deep serial).
//  - exact defer-rescale: when __any(mx>m) is false, alpha==1 exactly ->
//    skip exp2 + 17 muls (wave-uniform branch).
__global__ __launch_bounds__(256) void attn_kernel(
    const unsigned short* __restrict__ Qf, const unsigned short* __restrict__ Kf,
    const unsigned short* __restrict__ Vf, unsigned short* __restrict__ Opg,
    float* __restrict__ mlg)
{
    __shared__ __align__(16) unsigned short Pb[4][16][72];
    const int tid  = threadIdx.x;
    const int w    = tid >> 6;
    const int lane = tid & 63;
    const int quad = lane >> 4;
    const int c    = lane & 15;
    const int bid  = blockIdx.x;
    const int qt   = 255 - (bid & 255);       // qt descending within ks-group
    const int ks   = bid >> 8;
    const int g    = qt >> 5;                 // nseg-1
    if (ks > g) return;
    const int b    = w;                       // wave = batch (equal work lengths)
    const int q0   = qt * 16;
    const int k0   = ks * 512;
    const int kend = (q0 + 15 < k0 + 511) ? q0 + 15 : k0 + 511;

    // Q B-frags: coalesced 1KB wave loads from fragment-order Qf
    const unsigned short* qp = Qf + ((size_t)b * 256 + qt) * 1024 + lane * 8;
    const bf16x8 qB0 = *(const bf16x8*)qp;
    const bf16x8 qB1 = *(const bf16x8*)(qp + 512);

    f32x4 O[4];
#pragma unroll
    for (int tt = 0; tt < 4; tt++) O[tt] = {0.f, 0.f, 0.f, 0.f};
    float m = -1e30f, ls = 0.f;
    const float scale2 = 0.045084436f;        // (1/32)*log2(e): exp -> exp2

    unsigned short* P = &Pb[w][0][0];
    const int prow = c * 72;

    // preload first K chunk
    bf16x8 kC[8];
    {
        const unsigned short* kfb = Kf + ((size_t)b * 256 + (k0 >> 4)) * 1024 + lane * 8;
#pragma unroll
        for (int i = 0; i < 4; i++) {
            kC[2 * i]     = *(const bf16x8*)(kfb + i * 1024);
            kC[2 * i + 1] = *(const bf16x8*)(kfb + i * 1024 + 512);
        }
    }

    for (int kb = k0; kb <= kend; kb += 64) {
        f32x4 S[4];
#pragma unroll
        for (int tt = 0; tt < 4; tt++) {
            f32x4 s = {0.f, 0.f, 0.f, 0.f};
            s = __builtin_amdgcn_mfma_f32_16x16x32_bf16(kC[2 * tt],     qB0, s, 0, 0, 0);
            s = __builtin_amdgcn_mfma_f32_16x16x32_bf16(kC[2 * tt + 1], qB1, s, 0, 0, 0);
            S[tt] = s;
        }
        // in-place prefetch of next chunk's K (kC already consumed above);
        // latency hides under softmax + PV below.
        if (kb + 64 <= kend) {
            const unsigned short* kfb =
                Kf + ((size_t)b * 256 + ((kb + 64) >> 4)) * 1024 + lane * 8;
#pragma unroll
            for (int i = 0; i < 4; i++) {
                kC[2 * i]     = *(const bf16x8*)(kfb + i * 1024);
                kC[2 * i + 1] = *(const bf16x8*)(kfb + i * 1024 + 512);
            }
        }

        // mask + scale in place
        if (kb + 63 > q0) {                   // diagonal chunk: causal mask
#pragma unroll
            for (int tt = 0; tt < 4; tt++)
#pragma unroll
                for (int r = 0; r < 4; r++) {
                    const int key = kb + tt * 16 + quad * 4 + r;
                    const float v = S[tt][r] * scale2;
                    S[tt][r] = (key > q0 + c) ? -1e30f : v;
                }
        } else {
#pragma unroll
            for (int tt = 0; tt < 4; tt++)
#pragma unroll
                for (int r = 0; r < 4; r++) S[tt][r] *= scale2;
        }

        // depth-5 tree max (was 15-deep serial)
        float t0 = fmaxf(fmaxf(S[0][0], S[0][1]), fmaxf(S[0][2], S[0][3]));
        float t1 = fmaxf(fmaxf(S[1][0], S[1][1]), fmaxf(S[1][2], S[1][3]));
        float t2 = fmaxf(fmaxf(S[2][0], S[2][1]), fmaxf(S[2][2], S[2][3]));
        float t3 = fmaxf(fmaxf(S[3][0], S[3][1]), fmaxf(S[3][2], S[3][3]));
        float mx = fmaxf(fmaxf(t0, t1), fmaxf(t2, t3));
        mx = fmaxf(mx, __shfl_xor(mx, 16));
        mx = fmaxf(mx, __shfl_xor(mx, 32));

        // exact defer-rescale: alpha==1 when mx<=m for all lanes
        if (__any(mx > m)) {
            const float mn    = fmaxf(m, mx);
            const float alpha = exp2_hw(m - mn);
            m = mn;
            ls *= alpha;
#pragma unroll
            for (int tt = 0; tt < 4; tt++)
#pragma unroll
                for (int r = 0; r < 4; r++) O[tt][r] *= alpha;
        }

        // exp + P write; 4 independent partial-sum chains
        float lp0 = 0.f, lp1 = 0.f, lp2 = 0.f, lp3 = 0.f;
#pragma unroll
        for (int tt = 0; tt < 4; tt++) {
            u16x4 pk;
            float l = 0.f;
#pragma unroll
            for (int r = 0; r < 4; r++) {
                const float e = exp2_hw(S[tt][r] - m);
                l += e;
                pk[r] = f32_to_bf16(e);
            }
            if (tt == 0) lp0 = l; else if (tt == 1) lp1 = l;
            else if (tt == 2) lp2 = l; else lp3 = l;
            *(u16x4*)(P + prow + tt * 16 + quad * 4) = pk;   // P[query][key]
        }
        ls += (lp0 + lp1) + (lp2 + lp3);

        const bf16x8 pB0 = *(const bf16x8*)(P + prow + quad * 8);
        const bf16x8 pB1 = *(const bf16x8*)(P + prow + 32 + quad * 8);

        const unsigned short* vfb = Vf + ((size_t)b * 128 + (kb >> 5)) * 2048 + lane * 8;
#pragma unroll
        for (int tt = 0; tt < 4; tt++) {
            const bf16x8 vA0 = *(const bf16x8*)(vfb + tt * 512);
            const bf16x8 vA1 = *(const bf16x8*)(vfb + 2048 + tt * 512);
            O[tt] = __builtin_amdgcn_mfma_f32_16x16x32_bf16(vA0, pB0, O[tt], 0, 0, 0);
            O[tt] = __builtin_amdgcn_mfma_f32_16x16x32_bf16(vA1, pB1, O[tt], 0, 0, 0);
        }
    }

    ls += __shfl_xor(ls, 16);                 // total l for query c
    ls += __shfl_xor(ls, 32);

    const size_t ustore = (size_t)b * NUNIT_ + qt + 16 * g * (g - 1) + g * (qt & 31) + ks;
#pragma unroll
    for (int tt = 0; tt < 4; tt++) {
        u16x4 pk;
#pragma unroll
        for (int r = 0; r < 4; r++) pk[r] = f32_to_bf16(O[tt][r]);
        *(u16x4*)(Opg + ustore * 1024 + c * 64 + tt * 16 + quad * 4) = pk;
    }
    if (lane < 16) {
        mlg[ustore * 32 + c]      = m;        // log2-domain max
        mlg[ustore * 32 + 16 + c] = ls;
    }
}

// ---- Kernel 3: merge segments + normalize (unchanged) ----------------------
__global__ __launch_bounds__(256) void merge_kernel(
    const unsigned short* __restrict__ Opg, const float* __restrict__ mlg,
    float* __restrict__ out)
{
    const int idx = blockIdx.x;               // b*256 + qt
    const int b   = idx >> 8;
    const int qt  = idx & 255;
    const int g   = qt >> 5;
    const int nseg = g + 1;
    const size_t base = (size_t)b * NUNIT_ + qt + 16 * g * (g - 1) + g * (qt & 31);
    const int t  = threadIdx.x;
    const int h  = t & 63;
    const int rg = t >> 6;
#pragma unroll
    for (int i = 0; i < 4; i++) {
        const int row = rg * 4 + i;
        float M = -1e30f;
        for (int s = 0; s < nseg; s++) M = fmaxf(M, mlg[(base + s) * 32 + row]);
        float L = 0.f, val = 0.f;
        for (int s = 0; s < nseg; s++) {
            const float e = exp2_hw(mlg[(base + s) * 32 + row] - M);
            L   = fmaf(mlg[(base + s) * 32 + 16 + row], e, L);
            val = fmaf(bf16_to_f32(Opg[(base + s) * 1024 + row * 64 + h]), e, val);
        }
        out[((size_t)b * T_ + qt * 16 + row) * H_ + h] = val / L;
    }
}

extern "C" void kernel_launch(void* const* d_in, const int* in_sizes, int n_in,
                              void* d_out, int out_size, void* d_ws, size_t ws_size,
                              hipStream_t stream) {
    const float* x  = (const float*)d_in[0];
    const float* Wq = (const float*)d_in[1];
    const float* Wk = (const float*)d_in[2];
    const float* Wv = (const float*)d_in[3];
    float* out = (float*)d_out;

    // ws: Qf|Kf|Vf (2 MiB each) | Wt 384K | Opg 9.2 MiB | mlg 576K
    unsigned short* Qf = (unsigned short*)d_ws;
    unsigned short* Kf = Qf + (size_t)BT_ * H_;
    unsigned short* Vf = Kf + (size_t)BT_ * H_;
    unsigned short* Wt = Vf + (size_t)BT_ * H_;
    unsigned short* Opg = Wt + (size_t)192 * C_;
    float*          mlg = (float*)(Opg + (size_t)B_ * NUNIT_ * 1024);

    wconv_kernel<<<96, 256, 0, stream>>>(Wq, Wk, Wv, Wt);
    proj_kernel<<<1024, 256, 0, stream>>>(x, Wt, Qf, Kf, Vf);
    attn_kernel<<<2048, 256, 0, stream>>>(Qf, Kf, Vf, Opg, mlg);
    merge_kernel<<<1024, 256, 0, stream>>>(Opg, mlg, out);
}

// Round 3
// 171.500 us; speedup vs baseline: 1.0132x; 1.0132x over previous
//
#include <hip/hip_runtime.h>

constexpr int B_  = 4;
constexpr int T_  = 4096;
constexpr int C_  = 1024;
constexpr int H_  = 64;
constexpr int BT_ = B_ * T_;
constexpr int NUNIT_ = 1152;   // 512-key work units per batch: sum_qt (qt/32+1)

typedef __attribute__((ext_vector_type(4))) float f32x4;
typedef __attribute__((ext_vector_type(8))) short bf16x8;
typedef __attribute__((ext_vector_type(8))) unsigned short u16x8;
typedef __attribute__((ext_vector_type(4))) unsigned short u16x4;

__device__ __forceinline__ unsigned short f32_to_bf16(float f) {
    union { float f; unsigned int u; } v;
    v.f = f;
    unsigned int r = v.u + 0x7FFFu + ((v.u >> 16) & 1u);  // RNE
    return (unsigned short)(r >> 16);
}
__device__ __forceinline__ float bf16_to_f32(unsigned short us) {
    union { unsigned int u; float f; } v;
    v.u = (unsigned int)us << 16;
    return v.f;
}
// 2^x via v_exp_f32 (hardware transcendental); __exp2f does not exist in HIP.
__device__ __forceinline__ float exp2_hw(float x) {
    return __builtin_amdgcn_exp2f(x);
}

// ---- Kernel 0: W -> fragment-order Wt (unchanged) --------------------------
__global__ __launch_bounds__(256) void wconv_kernel(
    const float* __restrict__ Wq, const float* __restrict__ Wk,
    const float* __restrict__ Wv, unsigned short* __restrict__ Wt)
{
    const int tid  = threadIdx.x;
    const int wid  = blockIdx.x * 4 + (tid >> 6);   // 0..383 = 12 ntiles x 32 ksteps
    const int lane = tid & 63;
    const int q    = lane >> 4, c = lane & 15;
    const int ntile = wid >> 5;
    const int kstep = wid & 31;
    const int n = ntile * 16 + c;                   // 0..191
    const int m = n >> 6;
    const float* W = (m == 0) ? Wq : (m == 1) ? Wk : Wv;
    const int ncol = n & 63;
    const int k0 = kstep * 32 + q * 8;
    u16x8 pk;
#pragma unroll
    for (int j = 0; j < 8; j++) pk[j] = f32_to_bf16(W[(size_t)(k0 + j) * H_ + ncol]);
    *(u16x8*)(Wt + (size_t)wid * 512 + lane * 8) = pk;
}

// ---- Kernel 1: QKV projection, fused fragment-order epilogue ---------------
// Round-15: the 42-us invariant across 3 structures was the __syncthreads
// vmcnt(0) drain pinning x-prefetch depth at 1 (one outstanding wave-load
// per CU -> ~1 TB/s effective cold-miss rate). Fix:
//  - RAW s_barrier with manual lgkmcnt(0) only (LDS producer/consumer needs
//    lgkm; global x loads are self-consumed, no cross-wave ordering) ->
//    x loads stay in flight ACROSS barriers.
//  - static 4-deep register prefetch ring (named vr0..vr3, fully unrolled;
//    runtime-indexed ext_vector arrays would spill to scratch).
// Oldest load is ~3 iterations old at convert time -> latency covered.
__global__ __launch_bounds__(256, 4) void proj_kernel(
    const float* __restrict__ x, const unsigned short* __restrict__ Wt,
    unsigned short* __restrict__ Qf, unsigned short* __restrict__ Kf,
    unsigned short* __restrict__ Vf)
{
    __shared__ __align__(16) unsigned short xs[2][16][72];
    const int t    = threadIdx.x;
    const int r0   = blockIdx.x * 16;
    const int w    = t >> 6;             // 0..3
    const int lane = t & 63;
    const int quad = lane >> 4;
    const int c    = lane & 15;
    const int nh   = w * 48;             // wave's 48-col n-chunk
    const int row  = t >> 4;             // 16 rows, 16 threads/row
    const int koff = (t & 15) * 4;       // one f32x4 per thread per 64-col tile

    f32x4 acc[3];
#pragma unroll
    for (int j = 0; j < 3; j++) acc[j] = {0.f, 0.f, 0.f, 0.f};

    const float* xp = x + (size_t)(r0 + row) * C_ + koff;
    // 4-deep prefetch ring: vrS holds tile kk = o*256 + S*64
    f32x4 vr0 = *(const f32x4*)(xp);
    f32x4 vr1 = *(const f32x4*)(xp + 64);
    f32x4 vr2 = *(const f32x4*)(xp + 128);
    f32x4 vr3 = *(const f32x4*)(xp + 192);

    int p = 0;

#define PROJ_PHASE(V, KK)                                                      \
    {                                                                          \
        u16x4 pk0;                                                             \
        _Pragma("unroll")                                                      \
        for (int i = 0; i < 4; i++) pk0[i] = f32_to_bf16(V[i]);                \
        *(u16x4*)&xs[p][row][koff] = pk0;                                      \
        __builtin_amdgcn_sched_barrier(0);                                     \
        asm volatile("s_waitcnt lgkmcnt(0)" ::: "memory");                     \
        __builtin_amdgcn_s_barrier();                                          \
        __builtin_amdgcn_sched_barrier(0);                                     \
        if ((KK) + 256 < C_) V = *(const f32x4*)(xp + (KK) + 256);             \
        _Pragma("unroll")                                                      \
        for (int ks = 0; ks < 64; ks += 32) {                                  \
            const bf16x8 a0 = *(const bf16x8*)&xs[p][c][ks + quad * 8];        \
            const unsigned short* bp =                                         \
                Wt + ((size_t)(nh >> 4) * 32 + (((KK) + ks) >> 5)) * 512       \
                   + lane * 8;                                                 \
            _Pragma("unroll")                                                  \
            for (int j = 0; j < 3; j++) {                                      \
                const bf16x8 bj = *(const bf16x8*)(bp + (size_t)j * 32 * 512); \
                acc[j] = __builtin_amdgcn_mfma_f32_16x16x32_bf16(              \
                    a0, bj, acc[j], 0, 0, 0);                                  \
            }                                                                  \
        }                                                                      \
        p ^= 1;                                                                \
    }

#pragma unroll
    for (int o = 0; o < 4; o++) {
        const int kk0 = o * 256;
        PROJ_PHASE(vr0, kk0 + 0)
        PROJ_PHASE(vr1, kk0 + 64)
        PROJ_PHASE(vr2, kk0 + 128)
        PROJ_PHASE(vr3, kk0 + 192)
    }
#undef PROJ_PHASE

    // fused fragment-order epilogue (S = r0; 16-aligned)
    const int S   = r0;
    const int bS  = S >> 12;
    const int cc0 = quad * 4;
#pragma unroll
    for (int j = 0; j < 3; j++) {
        const int nt = nh + j * 16;   // wave-uniform matrix select
        if (nt < 128) {               // Q (nt<64) or K
            const int d0 = (nt < 64) ? nt : nt - 64;
            unsigned short* base = (nt < 64) ? Qf : Kf;
            const int t16  = (S & 4095) >> 4;
            const int half = d0 >> 5;
            const int q8   = ((d0 >> 4) & 1) * 2 + (c >> 3);
            const int j8   = c & 7;
            unsigned short* pq = base + ((size_t)(bS * 256 + t16)) * 1024
                               + half * 512 + q8 * 128 + j8;
#pragma unroll
            for (int r = 0; r < 4; r++) pq[(cc0 + r) * 8] = f32_to_bf16(acc[j][r]);
        } else {                      // V
            const int d0  = nt - 128;
            const int k32 = (S & 4095) >> 5;
            const int ht  = d0 >> 4;
            const int sq  = (S & 31) >> 3;   // 0 or 2
            unsigned short* pv = Vf + (((size_t)(bS * 128 + k32)) * 4 + ht) * 512 + c * 8;
#pragma unroll
            for (int r = 0; r < 4; r++) {
                const int cc = cc0 + r;
                pv[(sq + (cc >> 3)) * 128 + (cc & 7)] = f32_to_bf16(acc[j][r]);
            }
        }
    }
}

// ---- Kernel 2: causal flash attention (round-14 core, unchanged) -----------
// Unit = wave = (b, qt, ks). No __syncthreads anywhere (per-wave P buffer);
// K chunk double-buffered in place; tree max; 4-chain lsum; exact
// defer-rescale.
__global__ __launch_bounds__(256) void attn_kernel(
    const unsigned short* __restrict__ Qf, const unsigned short* __restrict__ Kf,
    const unsigned short* __restrict__ Vf, unsigned short* __restrict__ Opg,
    float* __restrict__ mlg)
{
    __shared__ __align__(16) unsigned short Pb[4][16][72];
    const int tid  = threadIdx.x;
    const int w    = tid >> 6;
    const int lane = tid & 63;
    const int quad = lane >> 4;
    const int c    = lane & 15;
    const int bid  = blockIdx.x;
    const int qt   = 255 - (bid & 255);       // qt descending within ks-group
    const int ks   = bid >> 8;
    const int g    = qt >> 5;                 // nseg-1
    if (ks > g) return;
    const int b    = w;                       // wave = batch (equal work lengths)
    const int q0   = qt * 16;
    const int k0   = ks * 512;
    const int kend = (q0 + 15 < k0 + 511) ? q0 + 15 : k0 + 511;

    // Q B-frags: coalesced 1KB wave loads from fragment-order Qf
    const unsigned short* qp = Qf + ((size_t)b * 256 + qt) * 1024 + lane * 8;
    const bf16x8 qB0 = *(const bf16x8*)qp;
    const bf16x8 qB1 = *(const bf16x8*)(qp + 512);

    f32x4 O[4];
#pragma unroll
    for (int tt = 0; tt < 4; tt++) O[tt] = {0.f, 0.f, 0.f, 0.f};
    float m = -1e30f, ls = 0.f;
    const float scale2 = 0.045084436f;        // (1/32)*log2(e): exp -> exp2

    unsigned short* P = &Pb[w][0][0];
    const int prow = c * 72;

    // preload first K chunk
    bf16x8 kC[8];
    {
        const unsigned short* kfb = Kf + ((size_t)b * 256 + (k0 >> 4)) * 1024 + lane * 8;
#pragma unroll
        for (int i = 0; i < 4; i++) {
            kC[2 * i]     = *(const bf16x8*)(kfb + i * 1024);
            kC[2 * i + 1] = *(const bf16x8*)(kfb + i * 1024 + 512);
        }
    }

    for (int kb = k0; kb <= kend; kb += 64) {
        f32x4 S[4];
#pragma unroll
        for (int tt = 0; tt < 4; tt++) {
            f32x4 s = {0.f, 0.f, 0.f, 0.f};
            s = __builtin_amdgcn_mfma_f32_16x16x32_bf16(kC[2 * tt],     qB0, s, 0, 0, 0);
            s = __builtin_amdgcn_mfma_f32_16x16x32_bf16(kC[2 * tt + 1], qB1, s, 0, 0, 0);
            S[tt] = s;
        }
        // in-place prefetch of next chunk's K (kC already consumed above);
        // latency hides under softmax + PV below.
        if (kb + 64 <= kend) {
            const unsigned short* kfb =
                Kf + ((size_t)b * 256 + ((kb + 64) >> 4)) * 1024 + lane * 8;
#pragma unroll
            for (int i = 0; i < 4; i++) {
                kC[2 * i]     = *(const bf16x8*)(kfb + i * 1024);
                kC[2 * i + 1] = *(const bf16x8*)(kfb + i * 1024 + 512);
            }
        }

        // mask + scale in place
        if (kb + 63 > q0) {                   // diagonal chunk: causal mask
#pragma unroll
            for (int tt = 0; tt < 4; tt++)
#pragma unroll
                for (int r = 0; r < 4; r++) {
                    const int key = kb + tt * 16 + quad * 4 + r;
                    const float v = S[tt][r] * scale2;
                    S[tt][r] = (key > q0 + c) ? -1e30f : v;
                }
        } else {
#pragma unroll
            for (int tt = 0; tt < 4; tt++)
#pragma unroll
                for (int r = 0; r < 4; r++) S[tt][r] *= scale2;
        }

        // depth-5 tree max (was 15-deep serial)
        float t0 = fmaxf(fmaxf(S[0][0], S[0][1]), fmaxf(S[0][2], S[0][3]));
        float t1 = fmaxf(fmaxf(S[1][0], S[1][1]), fmaxf(S[1][2], S[1][3]));
        float t2 = fmaxf(fmaxf(S[2][0], S[2][1]), fmaxf(S[2][2], S[2][3]));
        float t3 = fmaxf(fmaxf(S[3][0], S[3][1]), fmaxf(S[3][2], S[3][3]));
        float mx = fmaxf(fmaxf(t0, t1), fmaxf(t2, t3));
        mx = fmaxf(mx, __shfl_xor(mx, 16));
        mx = fmaxf(mx, __shfl_xor(mx, 32));

        // exact defer-rescale: alpha==1 when mx<=m for all lanes
        if (__any(mx > m)) {
            const float mn    = fmaxf(m, mx);
            const float alpha = exp2_hw(m - mn);
            m = mn;
            ls *= alpha;
#pragma unroll
            for (int tt = 0; tt < 4; tt++)
#pragma unroll
                for (int r = 0; r < 4; r++) O[tt][r] *= alpha;
        }

        // exp + P write; 4 independent partial-sum chains
        float lp0 = 0.f, lp1 = 0.f, lp2 = 0.f, lp3 = 0.f;
#pragma unroll
        for (int tt = 0; tt < 4; tt++) {
            u16x4 pk;
            float l = 0.f;
#pragma unroll
            for (int r = 0; r < 4; r++) {
                const float e = exp2_hw(S[tt][r] - m);
                l += e;
                pk[r] = f32_to_bf16(e);
            }
            if (tt == 0) lp0 = l; else if (tt == 1) lp1 = l;
            else if (tt == 2) lp2 = l; else lp3 = l;
            *(u16x4*)(P + prow + tt * 16 + quad * 4) = pk;   // P[query][key]
        }
        ls += (lp0 + lp1) + (lp2 + lp3);

        const bf16x8 pB0 = *(const bf16x8*)(P + prow + quad * 8);
        const bf16x8 pB1 = *(const bf16x8*)(P + prow + 32 + quad * 8);

        const unsigned short* vfb = Vf + ((size_t)b * 128 + (kb >> 5)) * 2048 + lane * 8;
#pragma unroll
        for (int tt = 0; tt < 4; tt++) {
            const bf16x8 vA0 = *(const bf16x8*)(vfb + tt * 512);
            const bf16x8 vA1 = *(const bf16x8*)(vfb + 2048 + tt * 512);
            O[tt] = __builtin_amdgcn_mfma_f32_16x16x32_bf16(vA0, pB0, O[tt], 0, 0, 0);
            O[tt] = __builtin_amdgcn_mfma_f32_16x16x32_bf16(vA1, pB1, O[tt], 0, 0, 0);
        }
    }

    ls += __shfl_xor(ls, 16);                 // total l for query c
    ls += __shfl_xor(ls, 32);

    const size_t ustore = (size_t)b * NUNIT_ + qt + 16 * g * (g - 1) + g * (qt & 31) + ks;
#pragma unroll
    for (int tt = 0; tt < 4; tt++) {
        u16x4 pk;
#pragma unroll
        for (int r = 0; r < 4; r++) pk[r] = f32_to_bf16(O[tt][r]);
        *(u16x4*)(Opg + ustore * 1024 + c * 64 + tt * 16 + quad * 4) = pk;
    }
    if (lane < 16) {
        mlg[ustore * 32 + c]      = m;        // log2-domain max
        mlg[ustore * 32 + 16 + c] = ls;
    }
}

// ---- Kernel 3: merge segments + normalize (unchanged) ----------------------
__global__ __launch_bounds__(256) void merge_kernel(
    const unsigned short* __restrict__ Opg, const float* __restrict__ mlg,
    float* __restrict__ out)
{
    const int idx = blockIdx.x;               // b*256 + qt
    const int b   = idx >> 8;
    const int qt  = idx & 255;
    const int g   = qt >> 5;
    const int nseg = g + 1;
    const size_t base = (size_t)b * NUNIT_ + qt + 16 * g * (g - 1) + g * (qt & 31);
    const int t  = threadIdx.x;
    const int h  = t & 63;
    const int rg = t >> 6;
#pragma unroll
    for (int i = 0; i < 4; i++) {
        const int row = rg * 4 + i;
        float M = -1e30f;
        for (int s = 0; s < nseg; s++) M = fmaxf(M, mlg[(base + s) * 32 + row]);
        float L = 0.f, val = 0.f;
        for (int s = 0; s < nseg; s++) {
            const float e = exp2_hw(mlg[(base + s) * 32 + row] - M);
            L   = fmaf(mlg[(base + s) * 32 + 16 + row], e, L);
            val = fmaf(bf16_to_f32(Opg[(base + s) * 1024 + row * 64 + h]), e, val);
        }
        out[((size_t)b * T_ + qt * 16 + row) * H_ + h] = val / L;
    }
}

extern "C" void kernel_launch(void* const* d_in, const int* in_sizes, int n_in,
                              void* d_out, int out_size, void* d_ws, size_t ws_size,
                              hipStream_t stream) {
    const float* x  = (const float*)d_in[0];
    const float* Wq = (const float*)d_in[1];
    const float* Wk = (const float*)d_in[2];
    const float* Wv = (const float*)d_in[3];
    float* out = (float*)d_out;

    // ws: Qf|Kf|Vf (2 MiB each) | Wt 384K | Opg 9.2 MiB | mlg 576K
    unsigned short* Qf = (unsigned short*)d_ws;
    unsigned short* Kf = Qf + (size_t)BT_ * H_;
    unsigned short* Vf = Kf + (size_t)BT_ * H_;
    unsigned short* Wt = Vf + (size_t)BT_ * H_;
    unsigned short* Opg = Wt + (size_t)192 * C_;
    float*          mlg = (float*)(Opg + (size_t)B_ * NUNIT_ * 1024);

    wconv_kernel<<<96, 256, 0, stream>>>(Wq, Wk, Wv, Wt);
    proj_kernel<<<1024, 256, 0, stream>>>(x, Wt, Qf, Kf, Vf);
    attn_kernel<<<2048, 256, 0, stream>>>(Qf, Kf, Vf, Opg, mlg);
    merge_kernel<<<1024, 256, 0, stream>>>(Opg, mlg, out);
}

// Round 4
// 165.547 us; speedup vs baseline: 1.0496x; 1.0360x over previous
//
#include <hip/hip_runtime.h>

constexpr int B_  = 4;
constexpr int T_  = 4096;
constexpr int C_  = 1024;
constexpr int H_  = 64;
constexpr int BT_ = B_ * T_;
constexpr int NUNIT_ = 1152;   // 512-key work units per batch: sum_qt (qt/32+1)

typedef __attribute__((ext_vector_type(4))) float f32x4;
typedef __attribute__((ext_vector_type(8))) short bf16x8;
typedef __attribute__((ext_vector_type(8))) unsigned short u16x8;
typedef __attribute__((ext_vector_type(4))) unsigned short u16x4;

__device__ __forceinline__ unsigned short f32_to_bf16(float f) {
    union { float f; unsigned int u; } v;
    v.f = f;
    unsigned int r = v.u + 0x7FFFu + ((v.u >> 16) & 1u);  // RNE
    return (unsigned short)(r >> 16);
}
__device__ __forceinline__ float bf16_to_f32(unsigned short us) {
    union { unsigned int u; float f; } v;
    v.u = (unsigned int)us << 16;
    return v.f;
}
// 2^x via v_exp_f32 (hardware transcendental); __exp2f does not exist in HIP.
__device__ __forceinline__ float exp2_hw(float x) {
    return __builtin_amdgcn_exp2f(x);
}

// ---- Kernel 0: W -> fragment-order Wt (unchanged) --------------------------
__global__ __launch_bounds__(256) void wconv_kernel(
    const float* __restrict__ Wq, const float* __restrict__ Wk,
    const float* __restrict__ Wv, unsigned short* __restrict__ Wt)
{
    const int tid  = threadIdx.x;
    const int wid  = blockIdx.x * 4 + (tid >> 6);   // 0..383 = 12 ntiles x 32 ksteps
    const int lane = tid & 63;
    const int q    = lane >> 4, c = lane & 15;
    const int ntile = wid >> 5;
    const int kstep = wid & 31;
    const int n = ntile * 16 + c;                   // 0..191
    const int m = n >> 6;
    const float* W = (m == 0) ? Wq : (m == 1) ? Wk : Wv;
    const int ncol = n & 63;
    const int k0 = kstep * 32 + q * 8;
    u16x8 pk;
#pragma unroll
    for (int j = 0; j < 8; j++) pk[j] = f32_to_bf16(W[(size_t)(k0 + j) * H_ + ncol]);
    *(u16x8*)(Wt + (size_t)wid * 512 + lane * 8) = pk;
}

// ---- Kernel 1: QKV projection, fused fragment-order epilogue ---------------
// Round-16: whole-panel single-stage. Rounds 13-15 all kept per-phase 256B
// wave-reads separated by barriers -> ~16K concurrent 256B DRAM streams ->
// ~1 TB/s effective; proj invariant at ~42 us across 3 structures. Now:
//  - each thread issues its 16 independent 16B loads back-to-back (p=0..15,
//    stride 256B along its row): per row the burst covers a full 4KB
//    sequential sweep, 16-deep per lane (~256KB in flight per CU).
//  - whole 16x1024 panel converted into 36KB LDS; ONE __syncthreads total
//    (its vmcnt(0) drain waits once for the whole burst - exactly what we
//    want); then 16 pure LDS+MFMA phases with zero barriers.
// Per-phase LDS write/read patterns unchanged from round-15 (known cheap).
__global__ __launch_bounds__(256, 4) void proj_kernel(
    const float* __restrict__ x, const unsigned short* __restrict__ Wt,
    unsigned short* __restrict__ Qf, unsigned short* __restrict__ Kf,
    unsigned short* __restrict__ Vf)
{
    __shared__ __align__(16) unsigned short xs[16][16][72];  // [phase][row][col+pad]
    const int t    = threadIdx.x;
    const int r0   = blockIdx.x * 16;
    const int w    = t >> 6;             // 0..3
    const int lane = t & 63;
    const int quad = lane >> 4;
    const int c    = lane & 15;
    const int nh   = w * 48;             // wave's 48-col n-chunk
    const int row  = t >> 4;             // 16 rows, 16 threads/row
    const int koff = (t & 15) * 4;       // one f32x4 per thread per 64-col tile

    // ---- stage: 16 loads in flight, convert as they arrive, one barrier ----
    const float* xp = x + (size_t)(r0 + row) * C_ + koff;
    f32x4 xv[16];                        // static-indexed (full unroll) -> regs
#pragma unroll
    for (int p = 0; p < 16; p++) xv[p] = *(const f32x4*)(xp + 64 * p);
#pragma unroll
    for (int p = 0; p < 16; p++) {
        u16x4 pk;
#pragma unroll
        for (int i = 0; i < 4; i++) pk[i] = f32_to_bf16(xv[p][i]);
        *(u16x4*)&xs[p][row][koff] = pk;
    }
    __syncthreads();                     // the only barrier in the kernel

    // ---- compute: 16 phases, pure LDS + MFMA, no barriers ----
    f32x4 acc[3];
#pragma unroll
    for (int j = 0; j < 3; j++) acc[j] = {0.f, 0.f, 0.f, 0.f};

#pragma unroll
    for (int p = 0; p < 16; p++) {
#pragma unroll
        for (int ks = 0; ks < 64; ks += 32) {
            const bf16x8 a0 = *(const bf16x8*)&xs[p][c][ks + quad * 8];
            const unsigned short* bp =
                Wt + ((size_t)(nh >> 4) * 32 + ((p * 64 + ks) >> 5)) * 512 + lane * 8;
#pragma unroll
            for (int j = 0; j < 3; j++) {
                const bf16x8 bj = *(const bf16x8*)(bp + (size_t)j * 32 * 512);
                acc[j] = __builtin_amdgcn_mfma_f32_16x16x32_bf16(a0, bj, acc[j], 0, 0, 0);
            }
        }
    }

    // fused fragment-order epilogue (S = r0; 16-aligned)
    const int S   = r0;
    const int bS  = S >> 12;
    const int cc0 = quad * 4;
#pragma unroll
    for (int j = 0; j < 3; j++) {
        const int nt = nh + j * 16;   // wave-uniform matrix select
        if (nt < 128) {               // Q (nt<64) or K
            const int d0 = (nt < 64) ? nt : nt - 64;
            unsigned short* base = (nt < 64) ? Qf : Kf;
            const int t16  = (S & 4095) >> 4;
            const int half = d0 >> 5;
            const int q8   = ((d0 >> 4) & 1) * 2 + (c >> 3);
            const int j8   = c & 7;
            unsigned short* pq = base + ((size_t)(bS * 256 + t16)) * 1024
                               + half * 512 + q8 * 128 + j8;
#pragma unroll
            for (int r = 0; r < 4; r++) pq[(cc0 + r) * 8] = f32_to_bf16(acc[j][r]);
        } else {                      // V
            const int d0  = nt - 128;
            const int k32 = (S & 4095) >> 5;
            const int ht  = d0 >> 4;
            const int sq  = (S & 31) >> 3;   // 0 or 2
            unsigned short* pv = Vf + (((size_t)(bS * 128 + k32)) * 4 + ht) * 512 + c * 8;
#pragma unroll
            for (int r = 0; r < 4; r++) {
                const int cc = cc0 + r;
                pv[(sq + (cc >> 3)) * 128 + (cc & 7)] = f32_to_bf16(acc[j][r]);
            }
        }
    }
}

// ---- Kernel 2: causal flash attention (round-14 core, unchanged) -----------
// Unit = wave = (b, qt, ks). No __syncthreads anywhere (per-wave P buffer);
// K chunk double-buffered in place; tree max; 4-chain lsum; exact
// defer-rescale.
__global__ __launch_bounds__(256) void attn_kernel(
    const unsigned short* __restrict__ Qf, const unsigned short* __restrict__ Kf,
    const unsigned short* __restrict__ Vf, unsigned short* __restrict__ Opg,
    float* __restrict__ mlg)
{
    __shared__ __align__(16) unsigned short Pb[4][16][72];
    const int tid  = threadIdx.x;
    const int w    = tid >> 6;
    const int lane = tid & 63;
    const int quad = lane >> 4;
    const int c    = lane & 15;
    const int bid  = blockIdx.x;
    const int qt   = 255 - (bid & 255);       // qt descending within ks-group
    const int ks   = bid >> 8;
    const int g    = qt >> 5;                 // nseg-1
    if (ks > g) return;
    const int b    = w;                       // wave = batch (equal work lengths)
    const int q0   = qt * 16;
    const int k0   = ks * 512;
    const int kend = (q0 + 15 < k0 + 511) ? q0 + 15 : k0 + 511;

    // Q B-frags: coalesced 1KB wave loads from fragment-order Qf
    const unsigned short* qp = Qf + ((size_t)b * 256 + qt) * 1024 + lane * 8;
    const bf16x8 qB0 = *(const bf16x8*)qp;
    const bf16x8 qB1 = *(const bf16x8*)(qp + 512);

    f32x4 O[4];
#pragma unroll
    for (int tt = 0; tt < 4; tt++) O[tt] = {0.f, 0.f, 0.f, 0.f};
    float m = -1e30f, ls = 0.f;
    const float scale2 = 0.045084436f;        // (1/32)*log2(e): exp -> exp2

    unsigned short* P = &Pb[w][0][0];
    const int prow = c * 72;

    // preload first K chunk
    bf16x8 kC[8];
    {
        const unsigned short* kfb = Kf + ((size_t)b * 256 + (k0 >> 4)) * 1024 + lane * 8;
#pragma unroll
        for (int i = 0; i < 4; i++) {
            kC[2 * i]     = *(const bf16x8*)(kfb + i * 1024);
            kC[2 * i + 1] = *(const bf16x8*)(kfb + i * 1024 + 512);
        }
    }

    for (int kb = k0; kb <= kend; kb += 64) {
        f32x4 S[4];
#pragma unroll
        for (int tt = 0; tt < 4; tt++) {
            f32x4 s = {0.f, 0.f, 0.f, 0.f};
            s = __builtin_amdgcn_mfma_f32_16x16x32_bf16(kC[2 * tt],     qB0, s, 0, 0, 0);
            s = __builtin_amdgcn_mfma_f32_16x16x32_bf16(kC[2 * tt + 1], qB1, s, 0, 0, 0);
            S[tt] = s;
        }
        // in-place prefetch of next chunk's K (kC already consumed above);
        // latency hides under softmax + PV below.
        if (kb + 64 <= kend) {
            const unsigned short* kfb =
                Kf + ((size_t)b * 256 + ((kb + 64) >> 4)) * 1024 + lane * 8;
#pragma unroll
            for (int i = 0; i < 4; i++) {
                kC[2 * i]     = *(const bf16x8*)(kfb + i * 1024);
                kC[2 * i + 1] = *(const bf16x8*)(kfb + i * 1024 + 512);
            }
        }

        // mask + scale in place
        if (kb + 63 > q0) {                   // diagonal chunk: causal mask
#pragma unroll
            for (int tt = 0; tt < 4; tt++)
#pragma unroll
                for (int r = 0; r < 4; r++) {
                    const int key = kb + tt * 16 + quad * 4 + r;
                    const float v = S[tt][r] * scale2;
                    S[tt][r] = (key > q0 + c) ? -1e30f : v;
                }
        } else {
#pragma unroll
            for (int tt = 0; tt < 4; tt++)
#pragma unroll
                for (int r = 0; r < 4; r++) S[tt][r] *= scale2;
        }

        // depth-5 tree max (was 15-deep serial)
        float t0 = fmaxf(fmaxf(S[0][0], S[0][1]), fmaxf(S[0][2], S[0][3]));
        float t1 = fmaxf(fmaxf(S[1][0], S[1][1]), fmaxf(S[1][2], S[1][3]));
        float t2 = fmaxf(fmaxf(S[2][0], S[2][1]), fmaxf(S[2][2], S[2][3]));
        float t3 = fmaxf(fmaxf(S[3][0], S[3][1]), fmaxf(S[3][2], S[3][3]));
        float mx = fmaxf(fmaxf(t0, t1), fmaxf(t2, t3));
        mx = fmaxf(mx, __shfl_xor(mx, 16));
        mx = fmaxf(mx, __shfl_xor(mx, 32));

        // exact defer-rescale: alpha==1 when mx<=m for all lanes
        if (__any(mx > m)) {
            const float mn    = fmaxf(m, mx);
            const float alpha = exp2_hw(m - mn);
            m = mn;
            ls *= alpha;
#pragma unroll
            for (int tt = 0; tt < 4; tt++)
#pragma unroll
                for (int r = 0; r < 4; r++) O[tt][r] *= alpha;
        }

        // exp + P write; 4 independent partial-sum chains
        float lp0 = 0.f, lp1 = 0.f, lp2 = 0.f, lp3 = 0.f;
#pragma unroll
        for (int tt = 0; tt < 4; tt++) {
            u16x4 pk;
            float l = 0.f;
#pragma unroll
            for (int r = 0; r < 4; r++) {
                const float e = exp2_hw(S[tt][r] - m);
                l += e;
                pk[r] = f32_to_bf16(e);
            }
            if (tt == 0) lp0 = l; else if (tt == 1) lp1 = l;
            else if (tt == 2) lp2 = l; else lp3 = l;
            *(u16x4*)(P + prow + tt * 16 + quad * 4) = pk;   // P[query][key]
        }
        ls += (lp0 + lp1) + (lp2 + lp3);

        const bf16x8 pB0 = *(const bf16x8*)(P + prow + quad * 8);
        const bf16x8 pB1 = *(const bf16x8*)(P + prow + 32 + quad * 8);

        const unsigned short* vfb = Vf + ((size_t)b * 128 + (kb >> 5)) * 2048 + lane * 8;
#pragma unroll
        for (int tt = 0; tt < 4; tt++) {
            const bf16x8 vA0 = *(const bf16x8*)(vfb + tt * 512);
            const bf16x8 vA1 = *(const bf16x8*)(vfb + 2048 + tt * 512);
            O[tt] = __builtin_amdgcn_mfma_f32_16x16x32_bf16(vA0, pB0, O[tt], 0, 0, 0);
            O[tt] = __builtin_amdgcn_mfma_f32_16x16x32_bf16(vA1, pB1, O[tt], 0, 0, 0);
        }
    }

    ls += __shfl_xor(ls, 16);                 // total l for query c
    ls += __shfl_xor(ls, 32);

    const size_t ustore = (size_t)b * NUNIT_ + qt + 16 * g * (g - 1) + g * (qt & 31) + ks;
#pragma unroll
    for (int tt = 0; tt < 4; tt++) {
        u16x4 pk;
#pragma unroll
        for (int r = 0; r < 4; r++) pk[r] = f32_to_bf16(O[tt][r]);
        *(u16x4*)(Opg + ustore * 1024 + c * 64 + tt * 16 + quad * 4) = pk;
    }
    if (lane < 16) {
        mlg[ustore * 32 + c]      = m;        // log2-domain max
        mlg[ustore * 32 + 16 + c] = ls;
    }
}

// ---- Kernel 3: merge segments + normalize (unchanged) ----------------------
__global__ __launch_bounds__(256) void merge_kernel(
    const unsigned short* __restrict__ Opg, const float* __restrict__ mlg,
    float* __restrict__ out)
{
    const int idx = blockIdx.x;               // b*256 + qt
    const int b   = idx >> 8;
    const int qt  = idx & 255;
    const int g   = qt >> 5;
    const int nseg = g + 1;
    const size_t base = (size_t)b * NUNIT_ + qt + 16 * g * (g - 1) + g * (qt & 31);
    const int t  = threadIdx.x;
    const int h  = t & 63;
    const int rg = t >> 6;
#pragma unroll
    for (int i = 0; i < 4; i++) {
        const int row = rg * 4 + i;
        float M = -1e30f;
        for (int s = 0; s < nseg; s++) M = fmaxf(M, mlg[(base + s) * 32 + row]);
        float L = 0.f, val = 0.f;
        for (int s = 0; s < nseg; s++) {
            const float e = exp2_hw(mlg[(base + s) * 32 + row] - M);
            L   = fmaf(mlg[(base + s) * 32 + 16 + row], e, L);
            val = fmaf(bf16_to_f32(Opg[(base + s) * 1024 + row * 64 + h]), e, val);
        }
        out[((size_t)b * T_ + qt * 16 + row) * H_ + h] = val / L;
    }
}

extern "C" void kernel_launch(void* const* d_in, const int* in_sizes, int n_in,
                              void* d_out, int out_size, void* d_ws, size_t ws_size,
                              hipStream_t stream) {
    const float* x  = (const float*)d_in[0];
    const float* Wq = (const float*)d_in[1];
    const float* Wk = (const float*)d_in[2];
    const float* Wv = (const float*)d_in[3];
    float* out = (float*)d_out;

    // ws: Qf|Kf|Vf (2 MiB each) | Wt 384K | Opg 9.2 MiB | mlg 576K
    unsigned short* Qf = (unsigned short*)d_ws;
    unsigned short* Kf = Qf + (size_t)BT_ * H_;
    unsigned short* Vf = Kf + (size_t)BT_ * H_;
    unsigned short* Wt = Vf + (size_t)BT_ * H_;
    unsigned short* Opg = Wt + (size_t)192 * C_;
    float*          mlg = (float*)(Opg + (size_t)B_ * NUNIT_ * 1024);

    wconv_kernel<<<96, 256, 0, stream>>>(Wq, Wk, Wv, Wt);
    proj_kernel<<<1024, 256, 0, stream>>>(x, Wt, Qf, Kf, Vf);
    attn_kernel<<<2048, 256, 0, stream>>>(Qf, Kf, Vf, Opg, mlg);
    merge_kernel<<<1024, 256, 0, stream>>>(Opg, mlg, out);
}